// Round 2
// baseline (85.839 us; speedup 1.0000x reference)
//
#include <hip/hip_runtime.h>
#include <hip/hip_bf16.h>

typedef __bf16 bf16x8 __attribute__((ext_vector_type(8)));
typedef float  f32x4  __attribute__((ext_vector_type(4)));
typedef float  f32x16 __attribute__((ext_vector_type(16)));

constexpr int Bn = 8192, Dn = 64, On = 256;

// async global->LDS DMA: dest = wave-uniform LDS base, HW adds lane*16
#define GLD16(g, l) __builtin_amdgcn_global_load_lds( \
    (const __attribute__((address_space(1))) void*)(g), \
    (__attribute__((address_space(3))) void*)(l), 16, 0, 0)

// ---- prep ----
// bTf[o][f][lane][8] : fragment-major bf16 A-image (same mapping as round-1):
//   af[f][j] for lane l = betas[o][d][e], e=(f>>2)*32+(l&31), d=((f&3)*2+(l>>5))*8+j
// ncpk[o][64] = -c_proj packed in 32x32 C-register order.
__global__ void k_prep(const float* __restrict__ betas, const float* __restrict__ centers,
                       __bf16* __restrict__ bTf, float* __restrict__ ncpk) {
    __shared__ float s[64 * 65];                        // +1 pad transpose buffer
    __shared__ float red[256];
    const int o = blockIdx.x, tid = threadIdx.x;
    const float* bo = betas + (size_t)o * 4096;         // betas[o][d][e]
    for (int j = tid; j < 1024; j += 256) {
        int d = j >> 4, e4 = (j & 15) * 4;
        float4 v = ((const float4*)bo)[j];
        s[d * 65 + e4 + 0] = v.x; s[d * 65 + e4 + 1] = v.y;
        s[d * 65 + e4 + 2] = v.z; s[d * 65 + e4 + 3] = v.w;
    }
    __syncthreads();
    // vectorized 16B bTf stores: 2 chunks of 8 bf16 per thread, coalesced
    for (int ch = tid; ch < 512; ch += 256) {
        int f = ch >> 6, l = ch & 63;
        int e  = ((f >> 2) << 5) + (l & 31);
        int db = (((f & 3) << 1) + (l >> 5)) * 8;
        bf16x8 v;
#pragma unroll
        for (int jj = 0; jj < 8; ++jj) v[jj] = (__bf16)s[(db + jj) * 65 + e];
        *(bf16x8*)(bTf + (size_t)o * 4096 + ch * 8) = v;
    }
    // -cproj, parallelized: thread t handles row(t&63), d-quarter (t>>6)
    {
        int t = tid & 63, part = tid >> 6;
        int et = t >> 5, rem = t & 31, l5r = rem >> 4, reg = rem & 15;
        int row = et * 32 + l5r * 4 + (reg & 3) + ((reg >> 2) << 3);
        float acc = 0.f;
#pragma unroll
        for (int d = part * 16; d < part * 16 + 16; ++d)
            acc += s[d * 65 + row] * centers[o * 64 + d];
        red[part * 64 + t] = acc;
    }
    __syncthreads();
    if (tid < 64)
        ncpk[o * 64 + tid] = -(red[tid] + red[64 + tid] + red[128 + tid] + red[192 + tid]);
}

// ---- main ----
// Block = 128 b x 8 o (all 4 waves share the o-set; wave wq owns b-rows wq*32..+31).
// A double-buffered in block-shared LDS (8 KB/o), DMA'd by all 4 waves, 1 barrier/o.
// Fragment-major A image => LDS re-read is lane*16B sequential (conflict-free).
// ~100 VGPR => 4 blocks/CU, 16 waves/CU: barrier/vmcnt drains covered by other blocks.
__global__ void __launch_bounds__(256, 4)
k_main(const float* __restrict__ x, const __bf16* __restrict__ bTf,
       const float* __restrict__ ncpk, float* __restrict__ out) {
    __shared__ __align__(16) __bf16 sX[128 * 64];       // 16 KB, xor-swizzled
    __shared__ __align__(16) __bf16 sA[2][4096];        // 2 x 8 KB A double-buffer
    __shared__ __align__(16) float  sCp[512];           // 2 KB: -cp for 8 o's

    const int tid = threadIdx.x, wq = tid >> 6, lane = tid & 63;
    const int l31 = lane & 31, l5 = lane >> 5;
    const int bbase = blockIdx.x * 128;
    const int o0 = blockIdx.y * 8;

    const __bf16* gA = bTf + (size_t)o0 * 4096;
    const int sl = wq * 1024;                           // wave's 2 KB DMA slice (elems)

    // prologue DMAs: A for oi=0 + all 8 o's of -cp (drained by the barrier)
    GLD16(gA + sl + lane * 8,       &sA[0][sl]);
    GLD16(gA + sl + 512 + lane * 8, &sA[0][sl + 512]);
    if (wq < 2) GLD16(ncpk + o0 * 64 + wq * 256 + lane * 4, sCp + wq * 256);

    // stage x fp32 -> bf16, chunk (rb, c) at slot c^(rb&7)
#pragma unroll
    for (int i = 0; i < 4; ++i) {
        int id = i * 256 + tid, rb = id >> 3, c = id & 7;
        const float* xp = x + (size_t)(bbase + rb) * 64 + c * 8;
        float4 v0 = *(const float4*)xp, v1 = *(const float4*)(xp + 4);
        bf16x8 f;
        f[0] = (__bf16)v0.x; f[1] = (__bf16)v0.y; f[2] = (__bf16)v0.z; f[3] = (__bf16)v0.w;
        f[4] = (__bf16)v1.x; f[5] = (__bf16)v1.y; f[6] = (__bf16)v1.z; f[7] = (__bf16)v1.w;
        *(bf16x8*)(sX + rb * 64 + ((c ^ (rb & 7)) << 3)) = f;
    }
    __syncthreads();                                    // sX + A[0] + sCp ready

    // resident x-fragments: B-operand, n = l31 within this wave's btile
    bf16x8 xf[4];
#pragma unroll
    for (int k = 0; k < 4; ++k) {
        int row = wq * 32 + l31, c = k * 2 + l5;
        xf[k] = *(const bf16x8*)(sX + row * 64 + ((c ^ (row & 7)) << 3));
    }

    f32x4 e0 = {0.f, 0.f, 0.f, 0.f}, e1 = {0.f, 0.f, 0.f, 0.f};
#pragma unroll
    for (int oi = 0; oi < 8; ++oi) {
        const __bf16* cb = &sA[oi & 1][0];
        if (oi < 7) {                                   // DMA next o's A into other buffer
            __bf16* nb = &sA[(oi + 1) & 1][0];
            GLD16(gA + (oi + 1) * 4096 + sl + lane * 8,       nb + sl);
            GLD16(gA + (oi + 1) * 4096 + sl + 512 + lane * 8, nb + sl + 512);
            __builtin_amdgcn_sched_barrier(0);          // pin DMA issue early
        }
        f32x4 qv = {0.f, 0.f, 0.f, 0.f};
#pragma unroll
        for (int et = 0; et < 2; ++et) {
            f32x16 cpv;                                 // C-init = -cp (broadcast reads)
#pragma unroll
            for (int r4 = 0; r4 < 4; ++r4)
                ((f32x4*)&cpv)[r4] = *(const f32x4*)(sCp + oi * 64 + et * 32 + l5 * 16 + r4 * 4);
            bf16x8 af[4];                               // conflict-free: lane*16B sequential
#pragma unroll
            for (int k = 0; k < 4; ++k)
                af[k] = *(const bf16x8*)(cb + (et * 4 + k) * 512 + lane * 8);
            f32x16 acc = __builtin_amdgcn_mfma_f32_32x32x16_bf16(af[0], xf[0], cpv, 0, 0, 0);
            acc = __builtin_amdgcn_mfma_f32_32x32x16_bf16(af[1], xf[1], acc, 0, 0, 0);
            acc = __builtin_amdgcn_mfma_f32_32x32x16_bf16(af[2], xf[2], acc, 0, 0, 0);
            acc = __builtin_amdgcn_mfma_f32_32x32x16_bf16(af[3], xf[3], acc, 0, 0, 0);
#pragma unroll
            for (int j = 0; j < 16; ++j)                // qv += (y-cp)^2
                qv[j & 3] = fmaf(acc[j], acc[j], qv[j & 3]);
        }
        float qs = (qv[0] + qv[1]) + (qv[2] + qv[3]);
        qs += __shfl_xor(qs, 32, 64);
        float ev = __expf(-qs);
        if (oi < 4) e0[oi] = ev; else e1[oi - 4] = ev;  // static idx (oi is unrolled const)
        if (oi < 7) __syncthreads();                    // next A landed + this buf consumed
    }

    // store: row b = bbase + wq*32 + l31 holds all 8 o's; split o-halves by l5
    const int b = bbase + wq * 32 + l31;
    float* op = out + (size_t)b * 256 + o0 + l5 * 4;
    *(f32x4*)op = l5 ? e1 : e0;
}

extern "C" void kernel_launch(void* const* d_in, const int* in_sizes, int n_in,
                              void* d_out, int out_size, void* d_ws, size_t ws_size,
                              hipStream_t stream) {
    const float* x       = (const float*)d_in[0];   // [8192,64]
    const float* centers = (const float*)d_in[1];   // [256,1,64]
    const float* betas   = (const float*)d_in[2];   // [256,64,64]
    float* out = (float*)d_out;                     // [8192,256] fp32

    char* ws = (char*)d_ws;
    __bf16* bTf  = (__bf16*)ws;                     // 2 MB (fragment-major A-images)
    float*  ncpk = (float*)(ws + 2 * (1 << 20));    // 64 KB (packed -cproj)

    k_prep<<<dim3(On),               dim3(256), 0, stream>>>(betas, centers, bTf, ncpk);
    k_main<<<dim3(Bn / 128, On / 8), dim3(256), 0, stream>>>(x, bTf, ncpk, out);
}